// Round 12
// baseline (247.367 us; speedup 1.0000x reference)
//
#include <hip/hip_runtime.h>

// SegmentLUT, float path. Straight-line 4-vec4 batch per thread:
//  - ALL 4 global_load_dwordx4 issued up front (4KB/wave in flight; HBM
//    latency overlaps LDS-table setup),
//  - compute,
//  - ALL stores at the end, then endpgm. No loop => no load ever waits
//    behind a store in the same wave (R9 lesson); stores drain cross-wave.
//  - grid 8192 blocks (vs 32768 one-shot): 4x fewer CP dispatches (R10 was
//    plausibly dispatch-rate-bound at ~520 blocks/us).
// Math per element:
//   xf  = med3(rint(x * 1/s), -32768, 32767)
//   idx = #{ j in 0..6 : segment_max[j] < xf }      (searchsorted left)
//   y   = med3(fma(kf[idx], xf, bf[idx]), olo, ohi)
// kf = alpha * 2^-rs * os, bf = ((beta<<ls)+rbias) * 2^-rs * os.
// absmax vs int reference: 0.125 (threshold 0.655).

typedef float f32x4 __attribute__((ext_vector_type(4)));

__device__ __forceinline__ float seg_one(float x, float inv_s,
                                         float sm0, float sm1, float sm2, float sm3,
                                         float sm4, float sm5, float sm6,
                                         const float2* tab, float olo, float ohi)
{
    float xf = rintf(x * inv_s);                           // v_mul + v_rndne (half-even)
    xf = __builtin_amdgcn_fmed3f(xf, -32768.0f, 32767.0f); // single-inst clamp
    int idx = (sm0 < xf) + (sm1 < xf) + (sm2 < xf) + (sm3 < xf)
            + (sm4 < xf) + (sm5 < xf) + (sm6 < xf);        // idx in [0,7]
    float2 t = tab[idx];                                   // ds_read_b64, conflict-free
    float y = fmaf(t.x, xf, t.y);
    return __builtin_amdgcn_fmed3f(y, olo, ohi);
}

__global__ __launch_bounds__(256) void SegmentLUT_83021717831949_kernel(
    const float* __restrict__ x,
    const float* __restrict__ input_scale,
    const float* __restrict__ out_scale,
    const int*   __restrict__ alpha,
    const int*   __restrict__ beta,
    const int*   __restrict__ lsh,
    const int*   __restrict__ rsh,
    const int*   __restrict__ smax,
    float*       __restrict__ out,
    int n)
{
    int nvec   = n >> 2;
    int stride = (int)(gridDim.x * blockDim.x);
    int i0 = (int)(blockIdx.x * blockDim.x + threadIdx.x);
    int i1 = i0 + stride, i2 = i0 + 2 * stride, i3 = i0 + 3 * stride;

    // Issue all batch loads FIRST: 4 global_load_dwordx4 in flight while the
    // table is built. (For this shape all lanes are valid; guards are for
    // generality and compile to exec-mask ops.)
    const f32x4* __restrict__ xv = (const f32x4*)x;
    f32x4 v0 = {}, v1 = {}, v2 = {}, v3 = {};
    if (i0 < nvec) v0 = xv[i0];
    if (i1 < nvec) v1 = xv[i1];
    if (i2 < nvec) v2 = xv[i2];
    if (i3 < nvec) v3 = xv[i3];

    __shared__ float2 tab[8];   // {kf, bf} per segment
    float os = out_scale[0];
    if (threadIdx.x < 8) {
        int j  = (int)threadIdx.x;
        int rs = rsh[j];
        int rm1 = rs - 1 > 0 ? rs - 1 : 0;
        int rbias = rs > 0 ? (1 << rm1) : 0;
        int bc = (int)((unsigned)beta[j] << (lsh[j] & 31)) + rbias;  // int32 wrap like ref
        float sc = ldexpf(os, -rs);                                   // os * 2^-rs
        tab[j] = make_float2((float)alpha[j] * sc, (float)bc * sc);
    }
    // Uniform values -> SGPRs (1 SGPR operand/VALU inst is free).
    float inv_s = 1.0f / input_scale[0];   // exact: s is a power of two (2^-13)
    float sm0 = (float)smax[0], sm1 = (float)smax[1], sm2 = (float)smax[2];
    float sm3 = (float)smax[3], sm4 = (float)smax[4], sm5 = (float)smax[5];
    float sm6 = (float)smax[6];
    float olo = -32768.0f * os, ohi = 32767.0f * os;
    __syncthreads();

#define SEG1(e) seg_one((e), inv_s, sm0, sm1, sm2, sm3, sm4, sm5, sm6, tab, olo, ohi)
#define SEG4(o, v) do { \
        (o).x = SEG1((v).x); (o).y = SEG1((v).y); \
        (o).z = SEG1((v).z); (o).w = SEG1((v).w); } while (0)

    f32x4 o0, o1, o2, o3;
    SEG4(o0, v0);
    SEG4(o1, v1);
    SEG4(o2, v2);
    SEG4(o3, v3);

    // All stores at the very end: nothing in this wave waits on them.
    f32x4* __restrict__ ov = (f32x4*)out;
    if (i0 < nvec) ov[i0] = o0;
    if (i1 < nvec) ov[i1] = o1;
    if (i2 < nvec) ov[i2] = o2;
    if (i3 < nvec) ov[i3] = o3;

    // Scalar tail for n % 4 != 0 (empty for this shape: n = 33554432).
    int ntail = n & 3;
    if (ntail && i0 < ntail) {
        int k = (nvec << 2) + i0;
        out[k] = SEG1(x[k]);
    }
#undef SEG4
#undef SEG1
}

extern "C" void kernel_launch(void* const* d_in, const int* in_sizes, int n_in,
                              void* d_out, int out_size, void* d_ws, size_t ws_size,
                              hipStream_t stream) {
    const float* x           = (const float*)d_in[0];
    const float* input_scale = (const float*)d_in[1];
    const float* out_scale   = (const float*)d_in[2];
    const int*   alpha       = (const int*)d_in[3];
    const int*   beta        = (const int*)d_in[4];
    const int*   lsh         = (const int*)d_in[5];
    const int*   rsh         = (const int*)d_in[6];
    const int*   smax        = (const int*)d_in[7];
    float* out = (float*)d_out;

    int n = in_sizes[0];
    int nvec = n >> 2;
    // 4 vec4 per thread, straight-line: grid covers nvec in one pass.
    int threads_needed = (nvec + 3) / 4;
    int blocks = (threads_needed + 255) / 256;   // 8192 for this shape
    if (blocks < 1) blocks = 1;

    SegmentLUT_83021717831949_kernel<<<blocks, 256, 0, stream>>>(
        x, input_scale, out_scale, alpha, beta, lsh, rsh, smax, out, n);
}

// Round 14
// 239.042 us; speedup vs baseline: 1.0348x; 1.0348x over previous
//
#include <hip/hip_runtime.h>

// SegmentLUT, two-kernel pure-stream design.
//  prep (1 block): builds 26 floats in d_ws:
//    [0..15] {kf_j, bf_j} = {alpha_j * 2^-rs_j * os, ((beta_j<<ls_j)+rbias_j) * 2^-rs_j * os}
//    [16] inv_s  [17] olo  [18] ohi  [19..25] segment_max[0..6] as float
//  main (32768 blocks, ONE float4 per thread — R10's winning shape):
//    uniform s_load of the 26 floats -> SGPRs (no LDS, no barrier, no per-block setup),
//    xf  = med3(rint(x * inv_s), -32768, 32767)
//    (k,b) selected by 7-step v_cndmask chain  (== searchsorted left)
//    y   = med3(fma(k, xf, b), olo, ohi)
//  R12 lesson: wave churn (1 load -> compute -> 1 store -> endpgm) is what
//  sustains BW; per-wave load batching got serialized at VGPR=32 and lost.
// absmax vs int reference: 0.125 (threshold 0.655).

typedef float f32x4 __attribute__((ext_vector_type(4)));

__global__ void SegmentLUT_83021717831949_prep(
    const float* __restrict__ input_scale,
    const float* __restrict__ out_scale,
    const int*   __restrict__ alpha,
    const int*   __restrict__ beta,
    const int*   __restrict__ lsh,
    const int*   __restrict__ rsh,
    const int*   __restrict__ smax,
    float*       __restrict__ ws)
{
    int j = (int)threadIdx.x;
    float os = out_scale[0];
    if (j < 8) {
        int rs = rsh[j];
        int rm1 = rs - 1 > 0 ? rs - 1 : 0;
        int rbias = rs > 0 ? (1 << rm1) : 0;
        int bc = (int)((unsigned)beta[j] << (lsh[j] & 31)) + rbias;  // int32 wrap like ref
        float sc = ldexpf(os, -rs);                                   // os * 2^-rs
        ws[2 * j]     = (float)alpha[j] * sc;   // kf_j
        ws[2 * j + 1] = (float)bc * sc;         // bf_j
    }
    if (j == 8)  ws[16] = 1.0f / input_scale[0];   // exact: s = 2^-13
    if (j == 9)  ws[17] = -32768.0f * os;
    if (j == 10) ws[18] =  32767.0f * os;
    if (j >= 11 && j < 18) ws[19 + (j - 11)] = (float)smax[j - 11];
}

__global__ __launch_bounds__(256) void SegmentLUT_83021717831949_kernel(
    const float* __restrict__ x,
    const float* __restrict__ ws,
    float*       __restrict__ out,
    int n)
{
    // Uniform loads with literal offsets, before any store and outside any
    // divergent branch -> scalarized to s_load, values live in SGPRs.
    float kf[8], bf[8];
#pragma unroll
    for (int j = 0; j < 8; ++j) { kf[j] = ws[2 * j]; bf[j] = ws[2 * j + 1]; }
    float inv_s = ws[16], olo = ws[17], ohi = ws[18];
    float smf[7];
#pragma unroll
    for (int j = 0; j < 7; ++j) smf[j] = ws[19 + j];

    int nvec = n >> 2;
    int i = (int)(blockIdx.x * blockDim.x + threadIdx.x);

    if (i < nvec) {
        f32x4 v = ((const f32x4*)x)[i];
        f32x4 o;
#pragma unroll
        for (int c = 0; c < 4; ++c) {
            float xf = rintf(v[c] * inv_s);                        // half-even like np.round
            xf = __builtin_amdgcn_fmed3f(xf, -32768.0f, 32767.0f); // clamp (qint16)
            // searchsorted left: first j with smax[j] >= xf, default 7.
            float k = kf[7], b = bf[7];
#pragma unroll
            for (int j = 6; j >= 0; --j) {
                bool csel = xf <= smf[j];          // v_cmp + 2x v_cndmask
                k = csel ? kf[j] : k;
                b = csel ? bf[j] : b;
            }
            o[c] = __builtin_amdgcn_fmed3f(fmaf(k, xf, b), olo, ohi);
        }
        ((f32x4*)out)[i] = o;
    }
    // Scalar tail for n % 4 != 0 (empty for this shape: n = 33554432).
    int ntail = n & 3;
    if (ntail && i < ntail) {
        int kidx = (nvec << 2) + i;
        float xf = rintf(x[kidx] * inv_s);
        xf = __builtin_amdgcn_fmed3f(xf, -32768.0f, 32767.0f);
        float k = kf[7], b = bf[7];
#pragma unroll
        for (int j = 6; j >= 0; --j) {
            bool csel = xf <= smf[j];
            k = csel ? kf[j] : k;
            b = csel ? bf[j] : b;
        }
        out[kidx] = __builtin_amdgcn_fmed3f(fmaf(k, xf, b), olo, ohi);
    }
}

extern "C" void kernel_launch(void* const* d_in, const int* in_sizes, int n_in,
                              void* d_out, int out_size, void* d_ws, size_t ws_size,
                              hipStream_t stream) {
    const float* x           = (const float*)d_in[0];
    const float* input_scale = (const float*)d_in[1];
    const float* out_scale   = (const float*)d_in[2];
    const int*   alpha       = (const int*)d_in[3];
    const int*   beta        = (const int*)d_in[4];
    const int*   lsh         = (const int*)d_in[5];
    const int*   rsh         = (const int*)d_in[6];
    const int*   smax        = (const int*)d_in[7];
    float* out = (float*)d_out;
    float* ws  = (float*)d_ws;   // 26 floats used

    int n = in_sizes[0];
    int nvec = n >> 2;
    int blocks = (nvec + 255) / 256;   // 32768 for this shape: 1 vec4/thread
    if (blocks < 1) blocks = 1;

    SegmentLUT_83021717831949_prep<<<1, 64, 0, stream>>>(
        input_scale, out_scale, alpha, beta, lsh, rsh, smax, ws);
    SegmentLUT_83021717831949_kernel<<<blocks, 256, 0, stream>>>(
        x, ws, out, n);
}